// Round 5
// baseline (4898.111 us; speedup 1.0000x reference)
//
#include <hip/hip_runtime.h>
#include <hip/hip_bf16.h>
#include <math.h>

// ViT + BiFormer forward. f32 I/O. All GEMMs use split-bf16 (hi+lo) triple-MFMA
// => ~1e-5 relative error (f32-grade) so the routing top-k never flips vs the
// f32 reference state. B=16, 197 tok, C=768, 12 heads, 12 layers, R=13, top-4.
//
// R1: gemm_nts: global_load_lds direct staging + split-K partial reduce.
// R2: attn_kernel MFMA-ized; aff_kernel wave-parallelized.
// R3: proj reduce+LN2 fused; aff+topk merged. (runtime-indexed dbuf REVERTED:
//     compiler can't prove DMA/ds_read non-aliasing -> conservative vmcnt(0)
//     before reads + 64KB occupancy cut => 79->154us.)
// R4: fused weight transposes (1 launch) — but layer-start placement made
//     W^T L2-cold by fc1 time: GEMM 79->106us at identical FETCH bytes.
// R5: counted-vmcnt double-buffer with STATICALLY NAMED LDS buffers (unroll x2,
//     all K-chunks have even iter counts; vmcnt(8) waits only the tile staged
//     one compute earlier — never a full drain in-loop). Transposes split into
//     two launches placed next to their consumer GEMMs.

typedef __bf16 bf16_t;
typedef __bf16 bf16x8 __attribute__((ext_vector_type(8)));
typedef __bf16 bf16x4 __attribute__((ext_vector_type(4)));
typedef __bf16 bf16x2v __attribute__((ext_vector_type(2)));
typedef float floatx4 __attribute__((ext_vector_type(4)));

static __device__ __forceinline__ float b2f(bf16_t x) { return (float)x; }
static __device__ __forceinline__ bf16_t f2b(float x) { return (bf16_t)x; }

#define AS1q __attribute__((address_space(1)))
#define AS3q __attribute__((address_space(3)))
static __device__ __forceinline__ void gll16(const bf16_t* g, bf16_t* l) {
    __builtin_amdgcn_global_load_lds((const AS1q void*)g, (AS3q void*)l, 16, 0, 0);
}

// combined W^T element offsets
#define OPRJ 1769472
#define OFC1 2359296
#define OFC2 4718592
#define WTSZ 7077888

// ---------------- transpose + hi/lo split: f32 [R,C] -> bf16 [C,R] x2 -----------
// generic (bounds-checked) version, used for the head weight only.
__global__ void transpose_split(const float* __restrict__ in, bf16_t* __restrict__ oh,
                                bf16_t* __restrict__ ol, int R, int C) {
    __shared__ float tile[32][33];
    int c0 = blockIdx.x * 32, r0 = blockIdx.y * 32;
    int tx = threadIdx.x, ty = threadIdx.y;  // (32,8)
#pragma unroll
    for (int i = 0; i < 4; i++) {
        int r = r0 + ty + i * 8;
        float v = 0.f;
        if (r < R && (c0 + tx) < C) v = in[(size_t)r * C + c0 + tx];
        tile[ty + i * 8][tx] = v;
    }
    __syncthreads();
#pragma unroll
    for (int i = 0; i < 4; i++) {
        int c = c0 + ty + i * 8;
        if (c < C && (r0 + tx) < R) {
            float v = tile[tx][ty + i * 8];
            bf16_t h = f2b(v);
            oh[(size_t)c * R + r0 + tx] = h;
            ol[(size_t)c * R + r0 + tx] = f2b(v - b2f(h));
        }
    }
}

// ---- fused per-layer weight transpose; id_off selects the section batch ----
// ids: [0,1728) qkv, [1728,2304) proj, [2304,4608) fc1, [4608,6912) fc2.
// launch A: grid 2304, id_off 0 (qkv+proj); launch B: grid 4608, id_off 2304.
__global__ void transpose_all(const float* __restrict__ qkvw,
                              const float* __restrict__ projw,
                              const float* __restrict__ fc1w,
                              const float* __restrict__ fc2w,
                              bf16_t* __restrict__ oh, bf16_t* __restrict__ ol,
                              int id_off) {
    __shared__ float tile[32][33];
    int id = blockIdx.x + id_off;
    const float* in; int R, C, ctiles; size_t ooff;
    if (id < 1728)      { in = qkvw;  R = 768;  C = 2304; ctiles = 72; ooff = 0; }
    else if (id < 2304) { id -= 1728; in = projw; R = 768;  C = 768;  ctiles = 24; ooff = OPRJ; }
    else if (id < 4608) { id -= 2304; in = fc1w;  R = 768;  C = 3072; ctiles = 96; ooff = OFC1; }
    else                { id -= 4608; in = fc2w;  R = 3072; C = 768;  ctiles = 24; ooff = OFC2; }
    int c0 = (id % ctiles) * 32, r0 = (id / ctiles) * 32;
    int tx = threadIdx.x, ty = threadIdx.y;  // (32,8)
#pragma unroll
    for (int i = 0; i < 4; i++)
        tile[ty + i * 8][tx] = in[(size_t)(r0 + ty + i * 8) * C + c0 + tx];
    __syncthreads();
#pragma unroll
    for (int i = 0; i < 4; i++) {
        int c = c0 + ty + i * 8;
        float v = tile[tx][ty + i * 8];
        bf16_t h = f2b(v);
        oh[ooff + (size_t)c * R + r0 + tx] = h;
        ol[ooff + (size_t)c * R + r0 + tx] = f2b(v - b2f(h));
    }
}

// ---------------- flat hi/lo split (conv_w is already [N,K]) ----------------
__global__ void split_kernel(const float* __restrict__ in, bf16_t* __restrict__ oh,
                             bf16_t* __restrict__ ol, int n) {
    int id = blockIdx.x * 256 + threadIdx.x;
    if (id < n) {
        float v = in[id];
        bf16_t h = f2b(v);
        oh[id] = h;
        ol[id] = f2b(v - b2f(h));
    }
}

// ---------------- im2col (16x16/stride16) with hi/lo split ----------------
__global__ void im2col_split(const float* __restrict__ x, bf16_t* __restrict__ oh,
                             bf16_t* __restrict__ ol) {
    int id = blockIdx.x * 256 + threadIdx.x;
    if (id >= 3136 * 768) return;
    int col = id % 768, row = id / 768;
    int b = row / 196, p = row % 196;
    int py = p / 14, px = p % 14;
    int c = col >> 8, rem = col & 255, ky = rem >> 4, kx = rem & 15;
    float v = x[(((size_t)(b * 3 + c)) * 224 + (py * 16 + ky)) * 224 + (px * 16 + kx)];
    bf16_t h = f2b(v);
    oh[id] = h;
    ol[id] = f2b(v - b2f(h));
}

// ---------------- cls token + pos_embed row 0 ----------------
__global__ void clspos_kernel(const float* __restrict__ cls, const float* __restrict__ pos,
                              float* __restrict__ t) {
    int id = blockIdx.x * 256 + threadIdx.x;  // 16*768
    int b = id / 768, c = id % 768;
    t[((size_t)(b * 197)) * 768 + c] = cls[c] + pos[c];
}

// ---------------- LayerNorm: f32 in -> hi/lo bf16 out (+ optional f32) ----------
__global__ __launch_bounds__(256) void ln_kernel(const float* __restrict__ in,
                                                 const float* __restrict__ g,
                                                 const float* __restrict__ bb,
                                                 bf16_t* __restrict__ oh,
                                                 bf16_t* __restrict__ ol,
                                                 float* __restrict__ outf) {
    int row = blockIdx.x;
    int t = threadIdx.x;
    const float* x = in + (size_t)row * 768;
    float v0 = x[t], v1 = x[t + 256], v2 = x[t + 512];
    float s = v0 + v1 + v2;
#pragma unroll
    for (int off = 32; off > 0; off >>= 1) s += __shfl_down(s, off, 64);
    __shared__ float red[8];
    int lane = t & 63, wave = t >> 6;
    if (lane == 0) red[wave] = s;
    __syncthreads();
    float mu = (red[0] + red[1] + red[2] + red[3]) * (1.f / 768.f);
    float d0 = v0 - mu, d1 = v1 - mu, d2 = v2 - mu;
    float vs = d0 * d0 + d1 * d1 + d2 * d2;
#pragma unroll
    for (int off = 32; off > 0; off >>= 1) vs += __shfl_down(vs, off, 64);
    if (lane == 0) red[4 + wave] = vs;
    __syncthreads();
    float var = (red[4] + red[5] + red[6] + red[7]) * (1.f / 768.f);
    float rstd = 1.0f / sqrtf(var + 1e-5f);
    float y0 = d0 * rstd * g[t] + bb[t];
    float y1 = d1 * rstd * g[t + 256] + bb[t + 256];
    float y2 = d2 * rstd * g[t + 512] + bb[t + 512];
    size_t base = (size_t)row * 768;
    bf16_t h0 = f2b(y0), h1 = f2b(y1), h2 = f2b(y2);
    oh[base + t] = h0; oh[base + t + 256] = h1; oh[base + t + 512] = h2;
    ol[base + t] = f2b(y0 - b2f(h0));
    ol[base + t + 256] = f2b(y1 - b2f(h1));
    ol[base + t + 512] = f2b(y2 - b2f(h2));
    if (outf) {
        outf[base + t] = y0; outf[base + t + 256] = y1; outf[base + t + 512] = y2;
    }
}

// ------- split-bf16 GEMM: C = (Ah+Al)[M,K] x (Bh+Bl)[N,K]^T --------------------
// 3 MFMAs per tile: Ah*Bh + Ah*Bl + Al*Bh  (drops Al*Bl ~ 2^-18 rel)
// Staging: global_load_lds dwordx4 into statically-named double buffers;
// counted s_waitcnt vmcnt(8) (= wait only the tile staged one compute-phase
// ago) + raw s_barrier. Loop unrolled x2; all Kc/32 counts are EVEN.
// K range: [kz*Kc, kz*Kc+Kc) with kz = blockIdx.z.
// mode 0: raw partial store at outF + kz*pstride; mode 1: outF = v + bias;
// mode 2: hi/lo(gelu(v + bias))
__global__ __launch_bounds__(256) void gemm_nts(const bf16_t* __restrict__ Ah,
                                                const bf16_t* __restrict__ Al,
                                                const bf16_t* __restrict__ Bh,
                                                const bf16_t* __restrict__ Bl,
                                                const float* __restrict__ bias,
                                                float* __restrict__ outF,
                                                bf16_t* __restrict__ outHi,
                                                bf16_t* __restrict__ outLo,
                                                int M, int N, int K, int Kc,
                                                size_t pstride, int mode) {
    __shared__ __align__(16) bf16_t Ash0[128 * 32], Asl0[128 * 32];
    __shared__ __align__(16) bf16_t Bsh0[128 * 32], Bsl0[128 * 32];
    __shared__ __align__(16) bf16_t Ash1[128 * 32], Asl1[128 * 32];
    __shared__ __align__(16) bf16_t Bsh1[128 * 32], Bsl1[128 * 32];
    const int t = threadIdx.x;
    const int lane = t & 63, wave = t >> 6;
    const int quad = lane >> 4, l16 = lane & 15;
    const int wm = (wave >> 1) * 64, wn = (wave & 1) * 64;
    const int m0 = blockIdx.y * 128, n0 = blockIdx.x * 128;
    const int kz = blockIdx.z;

    floatx4 acc[4][4];
#pragma unroll
    for (int i = 0; i < 4; i++)
#pragma unroll
        for (int j = 0; j < 4; j++)
#pragma unroll
            for (int p = 0; p < 4; p++) acc[i][j][p] = 0.f;

    // staging geometry: wave w covers rows [w*16, w*16+16); lane l -> row l>>2,
    // col (l&3)*8. LDS dest lane-linear. OOB rows read adjacent workspace
    // garbage -> feeds only discarded (m>=M / n>=N) outputs.
    const int sr = wave * 16 + (lane >> 2);
    const int sc = (lane & 3) * 8;
    const size_t a0 = (size_t)(m0 + sr) * K + sc;
    const size_t a1 = (size_t)(m0 + 64 + sr) * K + sc;
    const size_t b0 = (size_t)(n0 + sr) * K + sc;
    const size_t b1 = (size_t)(n0 + 64 + sr) * K + sc;
    const int lo0 = wave * 512;         // elems: rows [w*16 .. w*16+16)
    const int lo1 = 2048 + wave * 512;  // elems: rows [64+w*16 ..)

#define STAGE(AH, AL, BH, BL, kk) do {                      \
        gll16(Ah + a0 + (kk), AH + lo0);                    \
        gll16(Ah + a1 + (kk), AH + lo1);                    \
        gll16(Al + a0 + (kk), AL + lo0);                    \
        gll16(Al + a1 + (kk), AL + lo1);                    \
        gll16(Bh + b0 + (kk), BH + lo0);                    \
        gll16(Bh + b1 + (kk), BH + lo1);                    \
        gll16(Bl + b0 + (kk), BL + lo0);                    \
        gll16(Bl + b1 + (kk), BL + lo1);                    \
    } while (0)

#define COMPUTE(AH, AL, BH, BL) do {                                           \
        bf16x8 ah[4], al[4], bh[4], bl[4];                                     \
        _Pragma("unroll")                                                      \
        for (int i = 0; i < 4; i++) {                                          \
            ah[i] = *(const bf16x8*)&AH[(wm + i * 16 + l16) * 32 + quad * 8];  \
            al[i] = *(const bf16x8*)&AL[(wm + i * 16 + l16) * 32 + quad * 8];  \
        }                                                                      \
        _Pragma("unroll")                                                      \
        for (int j = 0; j < 4; j++) {                                          \
            bh[j] = *(const bf16x8*)&BH[(wn + j * 16 + l16) * 32 + quad * 8];  \
            bl[j] = *(const bf16x8*)&BL[(wn + j * 16 + l16) * 32 + quad * 8];  \
        }                                                                      \
        _Pragma("unroll")                                                      \
        for (int i = 0; i < 4; i++)                                            \
            _Pragma("unroll")                                                  \
            for (int j = 0; j < 4; j++) {                                      \
                acc[i][j] = __builtin_amdgcn_mfma_f32_16x16x32_bf16(ah[i], bh[j], acc[i][j], 0, 0, 0); \
                acc[i][j] = __builtin_amdgcn_mfma_f32_16x16x32_bf16(ah[i], bl[j], acc[i][j], 0, 0, 0); \
                acc[i][j] = __builtin_amdgcn_mfma_f32_16x16x32_bf16(al[i], bh[j], acc[i][j], 0, 0, 0); \
            }                                                                  \
    } while (0)

    const int kbeg = kz * Kc, kend = kbeg + Kc;
    STAGE(Ash0, Asl0, Bsh0, Bsl0, kbeg);          // 8 outstanding
    for (int k0 = kbeg; k0 < kend; k0 += 64) {
        STAGE(Ash1, Asl1, Bsh1, Bsl1, k0 + 32);   // 16 outstanding
        asm volatile("s_waitcnt vmcnt(8)" ::: "memory");   // buf0 landed
        __builtin_amdgcn_s_barrier();
        COMPUTE(Ash0, Asl0, Bsh0, Bsl0);
        __builtin_amdgcn_s_barrier();             // all reads of buf0 done
        if (k0 + 64 < kend) {
            STAGE(Ash0, Asl0, Bsh0, Bsl0, k0 + 64);
            asm volatile("s_waitcnt vmcnt(8)" ::: "memory");  // buf1 landed
        } else {
            asm volatile("s_waitcnt vmcnt(0)" ::: "memory");
        }
        __builtin_amdgcn_s_barrier();
        COMPUTE(Ash1, Asl1, Bsh1, Bsl1);
        __builtin_amdgcn_s_barrier();             // reads of buf1 done
    }
#undef STAGE
#undef COMPUTE

    float* Pp = outF + (size_t)kz * pstride;
#pragma unroll
    for (int i = 0; i < 4; i++) {
#pragma unroll
        for (int p = 0; p < 4; p++) {
            int m = m0 + wm + i * 16 + quad * 4 + p;
            if (m >= M) continue;
#pragma unroll
            for (int j = 0; j < 4; j++) {
                int n = n0 + wn + j * 16 + l16;
                if (n >= N) continue;
                if (mode == 0) {
                    Pp[(size_t)m * N + n] = acc[i][j][p];
                } else if (mode == 1) {
                    outF[(size_t)m * N + n] = acc[i][j][p] + bias[n];
                } else {  // mode 2: gelu -> hi/lo
                    float v = acc[i][j][p] + bias[n];
                    float gl = 0.5f * v * (1.0f + erff(v * 0.70710678118654752f));
                    bf16_t h = f2b(gl);
                    outHi[(size_t)m * N + n] = h;
                    outLo[(size_t)m * N + n] = f2b(gl - b2f(h));
                }
            }
        }
    }
}

// ---------------- split-K partial reduce + epilogue ----------------
// mode 0: out = sum + bias          (head)
// mode 1: out += sum + bias         (fc2 residual into tbuf)
// mode 2: embed: tbuf[(b*197+1+p)*N+n] = sum + bias + pos[(1+p)*N+n]
__global__ void reduce_kernel(const float* __restrict__ parts, int nchunks,
                              const float* __restrict__ bias, float* __restrict__ out,
                              const float* __restrict__ pos, int M, int N, int mode) {
    int id = blockIdx.x * 256 + threadIdx.x;
    int total = (M * N) >> 2;
    if (id >= total) return;
    size_t e = (size_t)id * 4;
    int n = (int)(e % N), m = (int)(e / N);
    size_t csz = (size_t)M * N;
    floatx4 s = *(const floatx4*)(parts + e);
    for (int c = 1; c < nchunks; c++) s += *(const floatx4*)(parts + (size_t)c * csz + e);
    s += *(const floatx4*)(bias + n);
    if (mode == 0) {
        *(floatx4*)(out + e) = s;
    } else if (mode == 1) {
        floatx4 o = *(const floatx4*)(out + e);
        *(floatx4*)(out + e) = o + s;
    } else {
        int b = m / 196, p = m % 196;
        floatx4 pv = *(const floatx4*)(pos + (size_t)(1 + p) * N + n);
        *(floatx4*)(out + ((size_t)(b * 197 + 1 + p)) * N + n) = s + pv;
    }
}

// ---------------- fused split-K reduce + bias + LayerNorm (proj path) ----------
__global__ __launch_bounds__(256) void reduce_ln_kernel(const float* __restrict__ parts,
                                                        int nchunks, size_t cstride,
                                                        const float* __restrict__ bias,
                                                        const float* __restrict__ g,
                                                        const float* __restrict__ bb,
                                                        bf16_t* __restrict__ oh,
                                                        bf16_t* __restrict__ ol) {
    int row = blockIdx.x;
    int t = threadIdx.x;
    float y0, y1, y2;
    {
        size_t base = (size_t)row * 768;
        float a0 = bias[t], a1 = bias[t + 256], a2 = bias[t + 512];
        for (int c = 0; c < nchunks; c++) {
            const float* p = parts + (size_t)c * cstride + base;
            a0 += p[t]; a1 += p[t + 256]; a2 += p[t + 512];
        }
        y0 = a0; y1 = a1; y2 = a2;
    }
    float s = y0 + y1 + y2;
#pragma unroll
    for (int off = 32; off > 0; off >>= 1) s += __shfl_down(s, off, 64);
    __shared__ float red[8];
    int lane = t & 63, wave = t >> 6;
    if (lane == 0) red[wave] = s;
    __syncthreads();
    float mu = (red[0] + red[1] + red[2] + red[3]) * (1.f / 768.f);
    float d0 = y0 - mu, d1 = y1 - mu, d2 = y2 - mu;
    float vs = d0 * d0 + d1 * d1 + d2 * d2;
#pragma unroll
    for (int off = 32; off > 0; off >>= 1) vs += __shfl_down(vs, off, 64);
    if (lane == 0) red[4 + wave] = vs;
    __syncthreads();
    float var = (red[4] + red[5] + red[6] + red[7]) * (1.f / 768.f);
    float rstd = 1.0f / sqrtf(var + 1e-5f);
    float z0 = d0 * rstd * g[t] + bb[t];
    float z1 = d1 * rstd * g[t + 256] + bb[t + 256];
    float z2 = d2 * rstd * g[t + 512] + bb[t + 512];
    size_t base = (size_t)row * 768;
    bf16_t h0 = f2b(z0), h1 = f2b(z1), h2 = f2b(z2);
    oh[base + t] = h0; oh[base + t + 256] = h1; oh[base + t + 512] = h2;
    ol[base + t] = f2b(z0 - b2f(h0));
    ol[base + t + 256] = f2b(z1 - b2f(h1));
    ol[base + t + 512] = f2b(z2 - b2f(h2));
}

// ---------------- region sums of f32 LN output: hsum[208][768] ----------------
__global__ void regsum_kernel(const float* __restrict__ h, float* __restrict__ hsum) {
    int bid = blockIdx.x;  // b*13 + r
    int b = bid / 13, r = bid % 13;
    int t = threadIdx.x;
#pragma unroll
    for (int j = 0; j < 3; j++) {
        int c = t + j * 256;
        float s = 0.f;
        for (int tt = 0; tt < 16; tt++) {
            int tp = r * 16 + tt;
            if (tp < 197) s += h[((size_t)(b * 197 + tp)) * 768 + c];
        }
        hsum[(size_t)bid * 768 + c] = s;
    }
}

// ---------------- routing GEMM (f32): qreg/kreg = (hsum @ Wqk + n_r*b) / 16 ------
__global__ __launch_bounds__(256) void qkreg_gemm(const float* __restrict__ hsum,
                                                  const float* __restrict__ W,
                                                  const float* __restrict__ bias,
                                                  float* __restrict__ qreg,
                                                  float* __restrict__ kreg) {
    __shared__ float A_s[16][33];
    __shared__ float B_s[32][68];
    const int t = threadIdx.x;
    const int m0 = blockIdx.y * 16;
    const int n0 = blockIdx.x * 64;
    const int m = t >> 4;
    const int nn = (t & 15) * 4;
    floatx4 acc;
    acc[0] = acc[1] = acc[2] = acc[3] = 0.f;

    for (int k0 = 0; k0 < 768; k0 += 32) {
        {
            int c = (t & 15) * 2;
            A_s[t >> 4][c]     = hsum[(size_t)(m0 + (t >> 4)) * 768 + k0 + c];
            A_s[t >> 4][c + 1] = hsum[(size_t)(m0 + (t >> 4)) * 768 + k0 + c + 1];
        }
        {
            int kr = t >> 3, cc = (t & 7) * 8;
            const float* src = W + (size_t)(k0 + kr) * 2304 + n0 + cc;
            floatx4 w0 = *(const floatx4*)src;
            floatx4 w1 = *(const floatx4*)(src + 4);
            *(floatx4*)&B_s[kr][cc] = w0;
            *(floatx4*)&B_s[kr][cc + 4] = w1;
        }
        __syncthreads();
#pragma unroll
        for (int kk = 0; kk < 32; kk++) {
            float a = A_s[m][kk];
            floatx4 bv = *(const floatx4*)&B_s[kk][nn];
            acc += a * bv;
        }
        __syncthreads();
    }

    int row = m0 + m;
    int r = row % 13;
    float nr = (r == 12) ? 5.f : 16.f;
#pragma unroll
    for (int j = 0; j < 4; j++) {
        int c = n0 + nn + j;
        float val = (acc[j] + nr * bias[c]) * 0.0625f;
        if (c < 768) qreg[(size_t)row * 768 + c] = val;
        else         kreg[(size_t)row * 768 + (c - 768)] = val;
    }
}

// ------- fused region affinity + top-4 (ties -> lowest index, = lax.top_k) ------
__global__ __launch_bounds__(256) void afftopk_kernel(const float* __restrict__ qreg,
                                                      const float* __restrict__ kreg,
                                                      int* __restrict__ idx) {
    __shared__ float arow[16];
    int br = blockIdx.x;              // b*13 + r
    int b = br / 13;
    int t = threadIdx.x, lane = t & 63, w = t >> 6;
    const float* qp = qreg + (size_t)br * 768;
    for (int s = w; s < 13; s += 4) {
        const float* kp = kreg + ((size_t)(b * 13 + s)) * 768;
        float a = 0.f;
#pragma unroll
        for (int jj = 0; jj < 3; jj++) {
            floatx4 q4 = *(const floatx4*)&qp[lane * 4 + jj * 256];
            floatx4 k4 = *(const floatx4*)&kp[lane * 4 + jj * 256];
            a += q4[0] * k4[0] + q4[1] * k4[1] + q4[2] * k4[2] + q4[3] * k4[3];
        }
#pragma unroll
        for (int msk = 32; msk >= 1; msk >>= 1) a += __shfl_xor(a, msk, 64);
        if (lane == 0) arow[s] = a;
    }
    __syncthreads();
    if (t == 0) {
        int mask = 0;
#pragma unroll
        for (int k = 0; k < 4; k++) {
            float best = -3.4e38f;
            int bi = 0;
            for (int s = 0; s < 13; s++) {
                if (!((mask >> s) & 1) && arow[s] > best) { best = arow[s]; bi = s; }
            }
            mask |= 1 << bi;
            idx[br * 4 + k] = bi;
        }
    }
}

// ---------------- gathered attention, MFMA version ----------------
__global__ __launch_bounds__(256) void attn_kernel(const float* __restrict__ qkv,
                                                   const int* __restrict__ idx,
                                                   bf16_t* __restrict__ oh,
                                                   bf16_t* __restrict__ ol) {
    __shared__ __align__(16) bf16_t Qh[16 * 72], Ql[16 * 72];
    __shared__ __align__(16) bf16_t Kh[64 * 72], Kl[64 * 72];
    __shared__ __align__(16) bf16_t Vth[64 * 68], Vtl[64 * 68];
    __shared__ __align__(16) float P_s[16 * 68];

    int bid = blockIdx.x;
    int head = bid % 12;
    int r = (bid / 12) % 13;
    int b = bid / (12 * 13);
    int t = threadIdx.x;
    const int lane = t & 63, wave = t >> 6;
    const int quad = lane >> 4, l16 = lane & 15;
    const int co = head * 64;
    const size_t rowb = (size_t)(b * 197);

    int regs[4];
#pragma unroll
    for (int j = 0; j < 4; j++) regs[j] = idx[(b * 13 + r) * 4 + j];

    {
        int rh = t >> 5;          // 0..7
        int c2 = (t & 31) * 2;    // 0..62
#pragma unroll
        for (int it = 0; it < 2; it++) {
            int m = rh + it * 8;
            int tp = r * 16 + m;
            float2 v; v.x = 0.f; v.y = 0.f;
            if (tp < 197) v = *(const float2*)&qkv[(rowb + tp) * 2304 + co + c2];
            bf16_t h0 = f2b(v.x), h1 = f2b(v.y);
            bf16x2v hh = {h0, h1};
            bf16x2v ll = {f2b(v.x - b2f(h0)), f2b(v.y - b2f(h1))};
            *(bf16x2v*)&Qh[m * 72 + c2] = hh;
            *(bf16x2v*)&Ql[m * 72 + c2] = ll;
        }
#pragma unroll
        for (int nb = 0; nb < 4; nb++) {
            int reg = regs[nb];
#pragma unroll
            for (int i2 = 0; i2 < 2; i2++) {
                int nn = rh + i2 * 8;
                int tp = reg * 16 + nn;
                int n = nb * 16 + nn;
                float2 v; v.x = 0.f; v.y = 0.f;
                if (tp < 197) v = *(const float2*)&qkv[(rowb + tp) * 2304 + 768 + co + c2];
                bf16_t h0 = f2b(v.x), h1 = f2b(v.y);
                bf16x2v hh = {h0, h1};
                bf16x2v ll = {f2b(v.x - b2f(h0)), f2b(v.y - b2f(h1))};
                *(bf16x2v*)&Kh[n * 72 + c2] = hh;
                *(bf16x2v*)&Kl[n * 72 + c2] = ll;
            }
        }
    }
    {
        int d = lane;
#pragma unroll
        for (int nb = 0; nb < 4; nb++) {
            int reg = regs[nb];
#pragma unroll
            for (int i2 = 0; i2 < 4; i2++) {
                int nn = wave + i2 * 4;
                int tp = reg * 16 + nn;
                int n = nb * 16 + nn;
                float v = (tp < 197) ? qkv[(rowb + tp) * 2304 + 1536 + co + d] : 0.f;
                bf16_t h = f2b(v);
                Vth[d * 68 + n] = h;
                Vtl[d * 68 + n] = f2b(v - b2f(h));
            }
        }
    }
    __syncthreads();

    {
        const int j = wave;
        bf16x8 qfh[2], qfl[2], kfh[2], kfl[2];
#pragma unroll
        for (int ks = 0; ks < 2; ks++) {
            qfh[ks] = *(const bf16x8*)&Qh[l16 * 72 + ks * 32 + quad * 8];
            qfl[ks] = *(const bf16x8*)&Ql[l16 * 72 + ks * 32 + quad * 8];
            kfh[ks] = *(const bf16x8*)&Kh[(j * 16 + l16) * 72 + ks * 32 + quad * 8];
            kfl[ks] = *(const bf16x8*)&Kl[(j * 16 + l16) * 72 + ks * 32 + quad * 8];
        }
        floatx4 s;
        s[0] = s[1] = s[2] = s[3] = 0.f;
#pragma unroll
        for (int ks = 0; ks < 2; ks++) {
            s = __builtin_amdgcn_mfma_f32_16x16x32_bf16(qfh[ks], kfh[ks], s, 0, 0, 0);
            s = __builtin_amdgcn_mfma_f32_16x16x32_bf16(qfh[ks], kfl[ks], s, 0, 0, 0);
            s = __builtin_amdgcn_mfma_f32_16x16x32_bf16(qfl[ks], kfh[ks], s, 0, 0, 0);
        }
#pragma unroll
        for (int p = 0; p < 4; p++)
            P_s[(quad * 4 + p) * 68 + j * 16 + l16] = s[p] * 0.125f;
    }
    __syncthreads();

    {
        int rw = t >> 4, c = t & 15;
        floatx4 v = *(const floatx4*)&P_s[rw * 68 + c * 4];
        float mx = fmaxf(fmaxf(v[0], v[1]), fmaxf(v[2], v[3]));
#pragma unroll
        for (int msk = 8; msk >= 1; msk >>= 1) mx = fmaxf(mx, __shfl_xor(mx, msk, 64));
        floatx4 e;
        e[0] = expf(v[0] - mx); e[1] = expf(v[1] - mx);
        e[2] = expf(v[2] - mx); e[3] = expf(v[3] - mx);
        float sm = e[0] + e[1] + e[2] + e[3];
#pragma unroll
        for (int msk = 8; msk >= 1; msk >>= 1) sm += __shfl_xor(sm, msk, 64);
        float inv = 1.f / sm;
        e[0] *= inv; e[1] *= inv; e[2] *= inv; e[3] *= inv;
        *(floatx4*)&P_s[rw * 68 + c * 4] = e;
    }
    __syncthreads();

    {
        const int j = wave;
        bf16x8 pfh[2], pfl[2], vfh[2], vfl[2];
#pragma unroll
        for (int ks = 0; ks < 2; ks++) {
            floatx4 p0 = *(const floatx4*)&P_s[l16 * 68 + ks * 32 + quad * 8];
            floatx4 p1 = *(const floatx4*)&P_s[l16 * 68 + ks * 32 + quad * 8 + 4];
#pragma unroll
            for (int i = 0; i < 4; i++) {
                float f0 = p0[i], f1 = p1[i];
                bf16_t h0 = f2b(f0), h1 = f2b(f1);
                pfh[ks][i] = h0;      pfh[ks][4 + i] = h1;
                pfl[ks][i] = f2b(f0 - b2f(h0));
                pfl[ks][4 + i] = f2b(f1 - b2f(h1));
            }
            int vrow = (j * 16 + l16) * 68 + ks * 32 + quad * 8;
            bf16x4 a0 = *(const bf16x4*)&Vth[vrow];
            bf16x4 a1 = *(const bf16x4*)&Vth[vrow + 4];
            bf16x4 c0 = *(const bf16x4*)&Vtl[vrow];
            bf16x4 c1 = *(const bf16x4*)&Vtl[vrow + 4];
#pragma unroll
            for (int i = 0; i < 4; i++) {
                vfh[ks][i] = a0[i]; vfh[ks][4 + i] = a1[i];
                vfl[ks][i] = c0[i]; vfl[ks][4 + i] = c1[i];
            }
        }
        floatx4 o;
        o[0] = o[1] = o[2] = o[3] = 0.f;
#pragma unroll
        for (int ks = 0; ks < 2; ks++) {
            o = __builtin_amdgcn_mfma_f32_16x16x32_bf16(pfh[ks], vfh[ks], o, 0, 0, 0);
            o = __builtin_amdgcn_mfma_f32_16x16x32_bf16(pfh[ks], vfl[ks], o, 0, 0, 0);
            o = __builtin_amdgcn_mfma_f32_16x16x32_bf16(pfl[ks], vfh[ks], o, 0, 0, 0);
        }
#pragma unroll
        for (int p = 0; p < 4; p++) {
            int m = quad * 4 + p;
            int tp = r * 16 + m;
            if (tp < 197) {
                size_t oidx = (rowb + tp) * 768 + co + j * 16 + l16;
                float f = o[p];
                bf16_t h = f2b(f);
                oh[oidx] = h;
                ol[oidx] = f2b(f - b2f(h));
            }
        }
    }
}

// ---------------- extract t[:,0] hi/lo for head GEMM ----------------
__global__ void headx_split(const float* __restrict__ t, bf16_t* __restrict__ oh,
                            bf16_t* __restrict__ ol) {
    int id = blockIdx.x * 256 + threadIdx.x;
    if (id >= 16 * 768) return;
    int b = id / 768, c = id % 768;
    float v = t[((size_t)(b * 197)) * 768 + c];
    bf16_t h = f2b(v);
    oh[id] = h;
    ol[id] = f2b(v - b2f(h));
}

extern "C" void kernel_launch(void* const* d_in, const int* in_sizes, int n_in,
                              void* d_out, int out_size, void* d_ws, size_t ws_size,
                              hipStream_t stream) {
    const float* x      = (const float*)d_in[0];
    const float* conv_w = (const float*)d_in[1];
    const float* conv_b = (const float*)d_in[2];
    const float* cls    = (const float*)d_in[3];
    const float* pos    = (const float*)d_in[4];
    const float* ln1g   = (const float*)d_in[5];
    const float* ln1b   = (const float*)d_in[6];
    const float* qkvw   = (const float*)d_in[7];
    const float* qkvb   = (const float*)d_in[8];
    const float* projw  = (const float*)d_in[9];
    const float* projb  = (const float*)d_in[10];
    const float* ln2g   = (const float*)d_in[11];
    const float* ln2b   = (const float*)d_in[12];
    const float* fc1w   = (const float*)d_in[13];
    const float* fc1b   = (const float*)d_in[14];
    const float* fc2w   = (const float*)d_in[15];
    const float* fc2b   = (const float*)d_in[16];
    const float* headw  = (const float*)d_in[17];
    const float* headb  = (const float*)d_in[18];
    float* out = (float*)d_out;

    char* ws = (char*)d_ws;
    size_t off = 0;
    auto alloc = [&](size_t bytes) -> void* {
        void* p = ws + off;
        off += (bytes + 255) & ~(size_t)255;
        return p;
    };
    // NOTE: allocation ORDER matters — fc2 split-K partials reuse the contiguous
    // dead region [h32, lnHi, lnLo, atHi, atLo] (= exactly 3 x 3152*768 floats).
    float*  tbuf   = (float*)alloc((size_t)3152 * 768 * 4);   // residual stream f32
    float*  h32    = (float*)alloc((size_t)3152 * 768 * 4);   // LN1 f32 out (routing)
    bf16_t* lnHi   = (bf16_t*)alloc((size_t)3152 * 768 * 2);
    bf16_t* lnLo   = (bf16_t*)alloc((size_t)3152 * 768 * 2);
    bf16_t* atHi   = (bf16_t*)alloc((size_t)3152 * 768 * 2);
    bf16_t* atLo   = (bf16_t*)alloc((size_t)3152 * 768 * 2);
    bf16_t* WhiT   = (bf16_t*)alloc((size_t)WTSZ * 2);        // combined layer W^T hi
    bf16_t* WloT   = (bf16_t*)alloc((size_t)WTSZ * 2);        // combined layer W^T lo
    char*   uni    = (char*)alloc((size_t)3152 * 3072 * 2 * 2);
    float*  qkvF   = (float*)uni;
    bf16_t* geHi   = (bf16_t*)uni;
    bf16_t* geLo   = geHi + (size_t)3152 * 3072;
    bf16_t* imHi   = (bf16_t*)uni;
    bf16_t* imLo   = imHi + (size_t)3136 * 768;
    float*  embPar = (float*)(uni + (size_t)3136 * 768 * 2 * 2);
    float*  hsum   = (float*)alloc((size_t)208 * 768 * 4);
    float*  qreg   = (float*)alloc((size_t)208 * 768 * 4);
    float*  kreg   = (float*)alloc((size_t)208 * 768 * 4);
    int*    idx    = (int*)alloc((size_t)832 * 4);
    bf16_t* hdHi   = (bf16_t*)alloc((size_t)16 * 768 * 2);
    bf16_t* hdLo   = (bf16_t*)alloc((size_t)16 * 768 * 2);
    alloc((size_t)1 << 18);  // pad: head GEMM staging reads past hdLo (rows to 127)
    if (off > ws_size) return;  // guard: output stays zero -> clear failure signal

    dim3 blk(256);
    dim3 tblk(32, 8);
    const int RED768 = (3152 * 768 / 4) / 256;   // 2364
    const int REDEMB = (3136 * 768 / 4) / 256;   // 2352
    const size_t PS = (size_t)3152 * 768;

    // ---- patch embed: split-K x3 (Kc=256), partials in uni tail ----
    im2col_split<<<dim3(9408), blk, 0, stream>>>(x, imHi, imLo);
    split_kernel<<<dim3(2304), blk, 0, stream>>>(conv_w, WhiT, WloT, 768 * 768);
    gemm_nts<<<dim3(6, 25, 3), blk, 0, stream>>>(imHi, imLo, WhiT, WloT, nullptr,
                                                 embPar, nullptr, nullptr,
                                                 3136, 768, 768, 256, (size_t)3136 * 768, 0);
    reduce_kernel<<<dim3(REDEMB), blk, 0, stream>>>(embPar, 3, conv_b, tbuf, pos,
                                                    3136, 768, 2);
    clspos_kernel<<<dim3(48), blk, 0, stream>>>(cls, pos, tbuf);

    for (int l = 0; l < 12; l++) {
        ln_kernel<<<dim3(3152), blk, 0, stream>>>(tbuf, ln1g + l * 768, ln1b + l * 768,
                                                  lnHi, lnLo, h32);

        // routing (f32 exact given state)
        regsum_kernel<<<dim3(208), blk, 0, stream>>>(h32, hsum);
        qkreg_gemm<<<dim3(24, 13), blk, 0, stream>>>(hsum, qkvw + (size_t)l * 768 * 2304,
                                                     qkvb + l * 2304, qreg, kreg);
        afftopk_kernel<<<dim3(208), blk, 0, stream>>>(qreg, kreg, idx);

        // qkv + proj weight transposes, right before the qkv GEMM (L2-warm)
        transpose_all<<<dim3(2304), tblk, 0, stream>>>(qkvw + (size_t)l * 768 * 2304,
                                                       projw + (size_t)l * 768 * 768,
                                                       fc1w + (size_t)l * 768 * 3072,
                                                       fc2w + (size_t)l * 3072 * 768,
                                                       WhiT, WloT, 0);

        // qkv GEMM -> f32 (450 wg, unsplit, mode 1)
        gemm_nts<<<dim3(18, 25, 1), blk, 0, stream>>>(lnHi, lnLo, WhiT, WloT,
                                                      qkvb + l * 2304, qkvF,
                                                      nullptr, nullptr,
                                                      3152, 2304, 768, 768, 0, 1);

        attn_kernel<<<dim3(16 * 13 * 12), blk, 0, stream>>>(qkvF, idx, atHi, atLo);

        // proj: split-K x4 (Kc=192), partials fill uni exactly (qkvF dead);
        // fused reduce + bias + LN2 -> lnHi/lnLo
        gemm_nts<<<dim3(6, 25, 4), blk, 0, stream>>>(atHi, atLo, WhiT + OPRJ, WloT + OPRJ,
                                                     nullptr, (float*)uni, nullptr, nullptr,
                                                     3152, 768, 768, 192, PS, 0);

        // fc1 + fc2 weight transposes, placed just before their GEMMs
        transpose_all<<<dim3(4608), tblk, 0, stream>>>(qkvw + (size_t)l * 768 * 2304,
                                                       projw + (size_t)l * 768 * 768,
                                                       fc1w + (size_t)l * 768 * 3072,
                                                       fc2w + (size_t)l * 3072 * 768,
                                                       WhiT, WloT, 2304);

        reduce_ln_kernel<<<dim3(3152), blk, 0, stream>>>((float*)uni, 4, PS,
                                                         projb + l * 768,
                                                         ln2g + l * 768, ln2b + l * 768,
                                                         lnHi, lnLo);

        // fc1 (600 wg, unsplit, gelu epilogue)
        gemm_nts<<<dim3(24, 25, 1), blk, 0, stream>>>(lnHi, lnLo, WhiT + OFC1, WloT + OFC1,
                                                      fc1b + l * 3072, nullptr,
                                                      geHi, geLo, 3152, 3072, 768, 768, 0, 2);

        // fc2: split-K x3 (Kc=1024), partials in dead [h32,lnHi,lnLo,atHi,atLo]
        gemm_nts<<<dim3(6, 25, 3), blk, 0, stream>>>(geHi, geLo, WhiT + OFC2, WloT + OFC2,
                                                     nullptr, h32, nullptr, nullptr,
                                                     3152, 768, 3072, 1024, PS, 0);
        reduce_kernel<<<dim3(RED768), blk, 0, stream>>>(h32, 3, fc2b + l * 768,
                                                        tbuf, nullptr, 3152, 768, 1);
    }

    // ---- classification head: split-K x3 (Kc=256), partials in hsum ----
    headx_split<<<dim3(48), blk, 0, stream>>>(tbuf, hdHi, hdLo);
    transpose_split<<<dim3(32, 24), tblk, 0, stream>>>(headw, WhiT, WloT, 768, 1000);
    gemm_nts<<<dim3(8, 1, 3), blk, 0, stream>>>(hdHi, hdLo, WhiT, WloT, nullptr,
                                                hsum, nullptr, nullptr,
                                                16, 1000, 768, 256, (size_t)16 * 1000, 0);
    reduce_kernel<<<dim3(16), blk, 0, stream>>>(hsum, 3, headb, out, nullptr,
                                                16, 1000, 0);
}

// Round 6
// 4407.653 us; speedup vs baseline: 1.1113x; 1.1113x over previous
//
#include <hip/hip_runtime.h>
#include <hip/hip_bf16.h>
#include <math.h>

// ViT + BiFormer forward. f32 I/O. All GEMMs use split-bf16 (hi+lo) triple-MFMA
// => ~1e-5 relative error (f32-grade) so the routing top-k never flips vs the
// f32 reference state. B=16, 197 tok, C=768, 12 heads, 12 layers, R=13, top-4.
//
// R1: gemm_nts: global_load_lds direct staging + split-K partial reduce.
// R2: attn_kernel MFMA-ized; aff wave-parallelized. (GEMM class: 79us)
// R3: proj reduce+LN2 fused; aff+topk merged. (dbuf REVERTED, 154us)
// R4: fused weight transposes at layer start — W^T L2-cold => GEMM 106us.
// R5: counted-vmcnt dbuf (static bufs) — occupancy 14% at 64KB LDS => 104us.
//     REVERTED. Conclusion: single-buffer 2-barrier + high adjacency wins.
// R6: R4 fusions + single-buffer GEMM + per-GEMM transpose adjacency (each
//     weight section transposed immediately before its consumer GEMM) +
//     bijective XCD-aware block swizzle (m204) on the GEMM x-y plane.

typedef __bf16 bf16_t;
typedef __bf16 bf16x8 __attribute__((ext_vector_type(8)));
typedef __bf16 bf16x4 __attribute__((ext_vector_type(4)));
typedef __bf16 bf16x2v __attribute__((ext_vector_type(2)));
typedef float floatx4 __attribute__((ext_vector_type(4)));

static __device__ __forceinline__ float b2f(bf16_t x) { return (float)x; }
static __device__ __forceinline__ bf16_t f2b(float x) { return (bf16_t)x; }

#define AS1q __attribute__((address_space(1)))
#define AS3q __attribute__((address_space(3)))
static __device__ __forceinline__ void gll16(const bf16_t* g, bf16_t* l) {
    __builtin_amdgcn_global_load_lds((const AS1q void*)g, (AS3q void*)l, 16, 0, 0);
}

// combined W^T element offsets
#define OPRJ 1769472
#define OFC1 2359296
#define OFC2 4718592
#define WTSZ 7077888

// ---------------- transpose + hi/lo split: f32 [R,C] -> bf16 [C,R] x2 -----------
// generic (bounds-checked) version, used for the head weight only.
__global__ void transpose_split(const float* __restrict__ in, bf16_t* __restrict__ oh,
                                bf16_t* __restrict__ ol, int R, int C) {
    __shared__ float tile[32][33];
    int c0 = blockIdx.x * 32, r0 = blockIdx.y * 32;
    int tx = threadIdx.x, ty = threadIdx.y;  // (32,8)
#pragma unroll
    for (int i = 0; i < 4; i++) {
        int r = r0 + ty + i * 8;
        float v = 0.f;
        if (r < R && (c0 + tx) < C) v = in[(size_t)r * C + c0 + tx];
        tile[ty + i * 8][tx] = v;
    }
    __syncthreads();
#pragma unroll
    for (int i = 0; i < 4; i++) {
        int c = c0 + ty + i * 8;
        if (c < C && (r0 + tx) < R) {
            float v = tile[tx][ty + i * 8];
            bf16_t h = f2b(v);
            oh[(size_t)c * R + r0 + tx] = h;
            ol[(size_t)c * R + r0 + tx] = f2b(v - b2f(h));
        }
    }
}

// ---- per-layer weight transpose; id_off selects the section ----
// ids: [0,1728) qkv, [1728,2304) proj, [2304,4608) fc1, [4608,6912) fc2.
// launched per-section, immediately before the consumer GEMM (L2 adjacency).
__global__ void transpose_all(const float* __restrict__ qkvw,
                              const float* __restrict__ projw,
                              const float* __restrict__ fc1w,
                              const float* __restrict__ fc2w,
                              bf16_t* __restrict__ oh, bf16_t* __restrict__ ol,
                              int id_off) {
    __shared__ float tile[32][33];
    int id = blockIdx.x + id_off;
    const float* in; int R, C, ctiles; size_t ooff;
    if (id < 1728)      { in = qkvw;  R = 768;  C = 2304; ctiles = 72; ooff = 0; }
    else if (id < 2304) { id -= 1728; in = projw; R = 768;  C = 768;  ctiles = 24; ooff = OPRJ; }
    else if (id < 4608) { id -= 2304; in = fc1w;  R = 768;  C = 3072; ctiles = 96; ooff = OFC1; }
    else                { id -= 4608; in = fc2w;  R = 3072; C = 768;  ctiles = 24; ooff = OFC2; }
    int c0 = (id % ctiles) * 32, r0 = (id / ctiles) * 32;
    int tx = threadIdx.x, ty = threadIdx.y;  // (32,8)
#pragma unroll
    for (int i = 0; i < 4; i++)
        tile[ty + i * 8][tx] = in[(size_t)(r0 + ty + i * 8) * C + c0 + tx];
    __syncthreads();
#pragma unroll
    for (int i = 0; i < 4; i++) {
        int c = c0 + ty + i * 8;
        float v = tile[tx][ty + i * 8];
        bf16_t h = f2b(v);
        oh[ooff + (size_t)c * R + r0 + tx] = h;
        ol[ooff + (size_t)c * R + r0 + tx] = f2b(v - b2f(h));
    }
}

// ---------------- flat hi/lo split (conv_w is already [N,K]) ----------------
__global__ void split_kernel(const float* __restrict__ in, bf16_t* __restrict__ oh,
                             bf16_t* __restrict__ ol, int n) {
    int id = blockIdx.x * 256 + threadIdx.x;
    if (id < n) {
        float v = in[id];
        bf16_t h = f2b(v);
        oh[id] = h;
        ol[id] = f2b(v - b2f(h));
    }
}

// ---------------- im2col (16x16/stride16) with hi/lo split ----------------
__global__ void im2col_split(const float* __restrict__ x, bf16_t* __restrict__ oh,
                             bf16_t* __restrict__ ol) {
    int id = blockIdx.x * 256 + threadIdx.x;
    if (id >= 3136 * 768) return;
    int col = id % 768, row = id / 768;
    int b = row / 196, p = row % 196;
    int py = p / 14, px = p % 14;
    int c = col >> 8, rem = col & 255, ky = rem >> 4, kx = rem & 15;
    float v = x[(((size_t)(b * 3 + c)) * 224 + (py * 16 + ky)) * 224 + (px * 16 + kx)];
    bf16_t h = f2b(v);
    oh[id] = h;
    ol[id] = f2b(v - b2f(h));
}

// ---------------- cls token + pos_embed row 0 ----------------
__global__ void clspos_kernel(const float* __restrict__ cls, const float* __restrict__ pos,
                              float* __restrict__ t) {
    int id = blockIdx.x * 256 + threadIdx.x;  // 16*768
    int b = id / 768, c = id % 768;
    t[((size_t)(b * 197)) * 768 + c] = cls[c] + pos[c];
}

// ---------------- LayerNorm: f32 in -> hi/lo bf16 out (+ optional f32) ----------
__global__ __launch_bounds__(256) void ln_kernel(const float* __restrict__ in,
                                                 const float* __restrict__ g,
                                                 const float* __restrict__ bb,
                                                 bf16_t* __restrict__ oh,
                                                 bf16_t* __restrict__ ol,
                                                 float* __restrict__ outf) {
    int row = blockIdx.x;
    int t = threadIdx.x;
    const float* x = in + (size_t)row * 768;
    float v0 = x[t], v1 = x[t + 256], v2 = x[t + 512];
    float s = v0 + v1 + v2;
#pragma unroll
    for (int off = 32; off > 0; off >>= 1) s += __shfl_down(s, off, 64);
    __shared__ float red[8];
    int lane = t & 63, wave = t >> 6;
    if (lane == 0) red[wave] = s;
    __syncthreads();
    float mu = (red[0] + red[1] + red[2] + red[3]) * (1.f / 768.f);
    float d0 = v0 - mu, d1 = v1 - mu, d2 = v2 - mu;
    float vs = d0 * d0 + d1 * d1 + d2 * d2;
#pragma unroll
    for (int off = 32; off > 0; off >>= 1) vs += __shfl_down(vs, off, 64);
    if (lane == 0) red[4 + wave] = vs;
    __syncthreads();
    float var = (red[4] + red[5] + red[6] + red[7]) * (1.f / 768.f);
    float rstd = 1.0f / sqrtf(var + 1e-5f);
    float y0 = d0 * rstd * g[t] + bb[t];
    float y1 = d1 * rstd * g[t + 256] + bb[t + 256];
    float y2 = d2 * rstd * g[t + 512] + bb[t + 512];
    size_t base = (size_t)row * 768;
    bf16_t h0 = f2b(y0), h1 = f2b(y1), h2 = f2b(y2);
    oh[base + t] = h0; oh[base + t + 256] = h1; oh[base + t + 512] = h2;
    ol[base + t] = f2b(y0 - b2f(h0));
    ol[base + t + 256] = f2b(y1 - b2f(h1));
    ol[base + t + 512] = f2b(y2 - b2f(h2));
    if (outf) {
        outf[base + t] = y0; outf[base + t + 256] = y1; outf[base + t + 512] = y2;
    }
}

// ------- split-bf16 GEMM: C = (Ah+Al)[M,K] x (Bh+Bl)[N,K]^T --------------------
// 3 MFMAs per tile: Ah*Bh + Ah*Bl + Al*Bh  (drops Al*Bl ~ 2^-18 rel)
// Staging: global_load_lds dwordx4, single-buffer linear [128][32] LDS (32KB),
// 2 barriers per 32-K step (proven R2 structure; both dbuf attempts regressed).
// Block x-y plane remapped with the bijective XCD swizzle (m204) for L2 reuse.
// K range: [kz*Kc, kz*Kc+Kc) with kz = blockIdx.z (Kc must divide K, mult 32).
// mode 0: raw partial store at outF + kz*pstride (reduce kernel finishes)
// mode 1: outF = v + bias
// mode 2: hi/lo(gelu(v + bias))
__global__ __launch_bounds__(256) void gemm_nts(const bf16_t* __restrict__ Ah,
                                                const bf16_t* __restrict__ Al,
                                                const bf16_t* __restrict__ Bh,
                                                const bf16_t* __restrict__ Bl,
                                                const float* __restrict__ bias,
                                                float* __restrict__ outF,
                                                bf16_t* __restrict__ outHi,
                                                bf16_t* __restrict__ outLo,
                                                int M, int N, int K, int Kc,
                                                size_t pstride, int mode) {
    __shared__ __align__(16) bf16_t Ash[128 * 32];
    __shared__ __align__(16) bf16_t Asl[128 * 32];
    __shared__ __align__(16) bf16_t Bsh[128 * 32];
    __shared__ __align__(16) bf16_t Bsl[128 * 32];
    const int t = threadIdx.x;
    const int lane = t & 63, wave = t >> 6;
    const int quad = lane >> 4, l16 = lane & 15;
    const int wm = (wave >> 1) * 64, wn = (wave & 1) * 64;

    // bijective XCD-aware remap of the x-y block plane (T1, m204 formula)
    const int nwg = gridDim.x * gridDim.y;
    const int lin = blockIdx.y * gridDim.x + blockIdx.x;
    const int qq = nwg >> 3, rr = nwg & 7;
    const int xcd = lin & 7, pos = lin >> 3;
    const int wgid = (xcd < rr ? xcd * (qq + 1) : rr * (qq + 1) + (xcd - rr) * qq) + pos;
    const int m0 = (wgid / gridDim.x) * 128;
    const int n0 = (wgid % gridDim.x) * 128;
    const int kz = blockIdx.z;

    floatx4 acc[4][4];
#pragma unroll
    for (int i = 0; i < 4; i++)
#pragma unroll
        for (int j = 0; j < 4; j++)
#pragma unroll
            for (int p = 0; p < 4; p++) acc[i][j][p] = 0.f;

    // staging geometry: wave w covers rows [w*16, w*16+16); lane l -> row l>>2,
    // col (l&3)*8. LDS dest lane-linear. OOB rows read adjacent workspace
    // garbage -> feeds only discarded (m>=M / n>=N) outputs.
    const int sr = wave * 16 + (lane >> 2);
    const int sc = (lane & 3) * 8;
    const size_t a0 = (size_t)(m0 + sr) * K + sc;
    const size_t a1 = (size_t)(m0 + 64 + sr) * K + sc;
    const size_t b0 = (size_t)(n0 + sr) * K + sc;
    const size_t b1 = (size_t)(n0 + 64 + sr) * K + sc;
    const int lo0 = wave * 512;         // elems: rows [w*16 .. w*16+16)
    const int lo1 = 2048 + wave * 512;  // elems: rows [64+w*16 ..)

    const int kend = kz * Kc + Kc;
    for (int k0 = kz * Kc; k0 < kend; k0 += 32) {
        __syncthreads();
        gll16(Ah + a0 + k0, Ash + lo0);
        gll16(Ah + a1 + k0, Ash + lo1);
        gll16(Al + a0 + k0, Asl + lo0);
        gll16(Al + a1 + k0, Asl + lo1);
        gll16(Bh + b0 + k0, Bsh + lo0);
        gll16(Bh + b1 + k0, Bsh + lo1);
        gll16(Bl + b0 + k0, Bsl + lo0);
        gll16(Bl + b1 + k0, Bsl + lo1);
        __syncthreads();  // compiler drains vmcnt before barrier
        bf16x8 ah[4], al[4], bh[4], bl[4];
#pragma unroll
        for (int i = 0; i < 4; i++) {
            ah[i] = *(const bf16x8*)&Ash[(wm + i * 16 + l16) * 32 + quad * 8];
            al[i] = *(const bf16x8*)&Asl[(wm + i * 16 + l16) * 32 + quad * 8];
        }
#pragma unroll
        for (int j = 0; j < 4; j++) {
            bh[j] = *(const bf16x8*)&Bsh[(wn + j * 16 + l16) * 32 + quad * 8];
            bl[j] = *(const bf16x8*)&Bsl[(wn + j * 16 + l16) * 32 + quad * 8];
        }
#pragma unroll
        for (int i = 0; i < 4; i++)
#pragma unroll
            for (int j = 0; j < 4; j++) {
                acc[i][j] = __builtin_amdgcn_mfma_f32_16x16x32_bf16(ah[i], bh[j], acc[i][j], 0, 0, 0);
                acc[i][j] = __builtin_amdgcn_mfma_f32_16x16x32_bf16(ah[i], bl[j], acc[i][j], 0, 0, 0);
                acc[i][j] = __builtin_amdgcn_mfma_f32_16x16x32_bf16(al[i], bh[j], acc[i][j], 0, 0, 0);
            }
    }

    float* Pp = outF + (size_t)kz * pstride;
#pragma unroll
    for (int i = 0; i < 4; i++) {
#pragma unroll
        for (int p = 0; p < 4; p++) {
            int m = m0 + wm + i * 16 + quad * 4 + p;
            if (m >= M) continue;
#pragma unroll
            for (int j = 0; j < 4; j++) {
                int n = n0 + wn + j * 16 + l16;
                if (n >= N) continue;
                if (mode == 0) {
                    Pp[(size_t)m * N + n] = acc[i][j][p];
                } else if (mode == 1) {
                    outF[(size_t)m * N + n] = acc[i][j][p] + bias[n];
                } else {  // mode 2: gelu -> hi/lo
                    float v = acc[i][j][p] + bias[n];
                    float gl = 0.5f * v * (1.0f + erff(v * 0.70710678118654752f));
                    bf16_t h = f2b(gl);
                    outHi[(size_t)m * N + n] = h;
                    outLo[(size_t)m * N + n] = f2b(gl - b2f(h));
                }
            }
        }
    }
}

// ---------------- split-K partial reduce + epilogue ----------------
// mode 0: out = sum + bias          (head)
// mode 1: out += sum + bias         (fc2 residual into tbuf)
// mode 2: embed: tbuf[(b*197+1+p)*N+n] = sum + bias + pos[(1+p)*N+n]
__global__ void reduce_kernel(const float* __restrict__ parts, int nchunks,
                              const float* __restrict__ bias, float* __restrict__ out,
                              const float* __restrict__ pos, int M, int N, int mode) {
    int id = blockIdx.x * 256 + threadIdx.x;
    int total = (M * N) >> 2;
    if (id >= total) return;
    size_t e = (size_t)id * 4;
    int n = (int)(e % N), m = (int)(e / N);
    size_t csz = (size_t)M * N;
    floatx4 s = *(const floatx4*)(parts + e);
    for (int c = 1; c < nchunks; c++) s += *(const floatx4*)(parts + (size_t)c * csz + e);
    s += *(const floatx4*)(bias + n);
    if (mode == 0) {
        *(floatx4*)(out + e) = s;
    } else if (mode == 1) {
        floatx4 o = *(const floatx4*)(out + e);
        *(floatx4*)(out + e) = o + s;
    } else {
        int b = m / 196, p = m % 196;
        floatx4 pv = *(const floatx4*)(pos + (size_t)(1 + p) * N + n);
        *(floatx4*)(out + ((size_t)(b * 197 + 1 + p)) * N + n) = s + pv;
    }
}

// ---------------- fused split-K reduce + bias + LayerNorm (proj path) ----------
__global__ __launch_bounds__(256) void reduce_ln_kernel(const float* __restrict__ parts,
                                                        int nchunks, size_t cstride,
                                                        const float* __restrict__ bias,
                                                        const float* __restrict__ g,
                                                        const float* __restrict__ bb,
                                                        bf16_t* __restrict__ oh,
                                                        bf16_t* __restrict__ ol) {
    int row = blockIdx.x;
    int t = threadIdx.x;
    float y0, y1, y2;
    {
        size_t base = (size_t)row * 768;
        float a0 = bias[t], a1 = bias[t + 256], a2 = bias[t + 512];
        for (int c = 0; c < nchunks; c++) {
            const float* p = parts + (size_t)c * cstride + base;
            a0 += p[t]; a1 += p[t + 256]; a2 += p[t + 512];
        }
        y0 = a0; y1 = a1; y2 = a2;
    }
    float s = y0 + y1 + y2;
#pragma unroll
    for (int off = 32; off > 0; off >>= 1) s += __shfl_down(s, off, 64);
    __shared__ float red[8];
    int lane = t & 63, wave = t >> 6;
    if (lane == 0) red[wave] = s;
    __syncthreads();
    float mu = (red[0] + red[1] + red[2] + red[3]) * (1.f / 768.f);
    float d0 = y0 - mu, d1 = y1 - mu, d2 = y2 - mu;
    float vs = d0 * d0 + d1 * d1 + d2 * d2;
#pragma unroll
    for (int off = 32; off > 0; off >>= 1) vs += __shfl_down(vs, off, 64);
    if (lane == 0) red[4 + wave] = vs;
    __syncthreads();
    float var = (red[4] + red[5] + red[6] + red[7]) * (1.f / 768.f);
    float rstd = 1.0f / sqrtf(var + 1e-5f);
    float z0 = d0 * rstd * g[t] + bb[t];
    float z1 = d1 * rstd * g[t + 256] + bb[t + 256];
    float z2 = d2 * rstd * g[t + 512] + bb[t + 512];
    size_t base = (size_t)row * 768;
    bf16_t h0 = f2b(z0), h1 = f2b(z1), h2 = f2b(z2);
    oh[base + t] = h0; oh[base + t + 256] = h1; oh[base + t + 512] = h2;
    ol[base + t] = f2b(z0 - b2f(h0));
    ol[base + t + 256] = f2b(z1 - b2f(h1));
    ol[base + t + 512] = f2b(z2 - b2f(h2));
}

// ---------------- region sums of f32 LN output: hsum[208][768] ----------------
__global__ void regsum_kernel(const float* __restrict__ h, float* __restrict__ hsum) {
    int bid = blockIdx.x;  // b*13 + r
    int b = bid / 13, r = bid % 13;
    int t = threadIdx.x;
#pragma unroll
    for (int j = 0; j < 3; j++) {
        int c = t + j * 256;
        float s = 0.f;
        for (int tt = 0; tt < 16; tt++) {
            int tp = r * 16 + tt;
            if (tp < 197) s += h[((size_t)(b * 197 + tp)) * 768 + c];
        }
        hsum[(size_t)bid * 768 + c] = s;
    }
}

// ---------------- routing GEMM (f32): qreg/kreg = (hsum @ Wqk + n_r*b) / 16 ------
__global__ __launch_bounds__(256) void qkreg_gemm(const float* __restrict__ hsum,
                                                  const float* __restrict__ W,
                                                  const float* __restrict__ bias,
                                                  float* __restrict__ qreg,
                                                  float* __restrict__ kreg) {
    __shared__ float A_s[16][33];
    __shared__ float B_s[32][68];
    const int t = threadIdx.x;
    const int m0 = blockIdx.y * 16;
    const int n0 = blockIdx.x * 64;
    const int m = t >> 4;
    const int nn = (t & 15) * 4;
    floatx4 acc;
    acc[0] = acc[1] = acc[2] = acc[3] = 0.f;

    for (int k0 = 0; k0 < 768; k0 += 32) {
        {
            int c = (t & 15) * 2;
            A_s[t >> 4][c]     = hsum[(size_t)(m0 + (t >> 4)) * 768 + k0 + c];
            A_s[t >> 4][c + 1] = hsum[(size_t)(m0 + (t >> 4)) * 768 + k0 + c + 1];
        }
        {
            int kr = t >> 3, cc = (t & 7) * 8;
            const float* src = W + (size_t)(k0 + kr) * 2304 + n0 + cc;
            floatx4 w0 = *(const floatx4*)src;
            floatx4 w1 = *(const floatx4*)(src + 4);
            *(floatx4*)&B_s[kr][cc] = w0;
            *(floatx4*)&B_s[kr][cc + 4] = w1;
        }
        __syncthreads();
#pragma unroll
        for (int kk = 0; kk < 32; kk++) {
            float a = A_s[m][kk];
            floatx4 bv = *(const floatx4*)&B_s[kk][nn];
            acc += a * bv;
        }
        __syncthreads();
    }

    int row = m0 + m;
    int r = row % 13;
    float nr = (r == 12) ? 5.f : 16.f;
#pragma unroll
    for (int j = 0; j < 4; j++) {
        int c = n0 + nn + j;
        float val = (acc[j] + nr * bias[c]) * 0.0625f;
        if (c < 768) qreg[(size_t)row * 768 + c] = val;
        else         kreg[(size_t)row * 768 + (c - 768)] = val;
    }
}

// ------- fused region affinity + top-4 (ties -> lowest index, = lax.top_k) ------
__global__ __launch_bounds__(256) void afftopk_kernel(const float* __restrict__ qreg,
                                                      const float* __restrict__ kreg,
                                                      int* __restrict__ idx) {
    __shared__ float arow[16];
    int br = blockIdx.x;              // b*13 + r
    int b = br / 13;
    int t = threadIdx.x, lane = t & 63, w = t >> 6;
    const float* qp = qreg + (size_t)br * 768;
    for (int s = w; s < 13; s += 4) {
        const float* kp = kreg + ((size_t)(b * 13 + s)) * 768;
        float a = 0.f;
#pragma unroll
        for (int jj = 0; jj < 3; jj++) {
            floatx4 q4 = *(const floatx4*)&qp[lane * 4 + jj * 256];
            floatx4 k4 = *(const floatx4*)&kp[lane * 4 + jj * 256];
            a += q4[0] * k4[0] + q4[1] * k4[1] + q4[2] * k4[2] + q4[3] * k4[3];
        }
#pragma unroll
        for (int msk = 32; msk >= 1; msk >>= 1) a += __shfl_xor(a, msk, 64);
        if (lane == 0) arow[s] = a;
    }
    __syncthreads();
    if (t == 0) {
        int mask = 0;
#pragma unroll
        for (int k = 0; k < 4; k++) {
            float best = -3.4e38f;
            int bi = 0;
            for (int s = 0; s < 13; s++) {
                if (!((mask >> s) & 1) && arow[s] > best) { best = arow[s]; bi = s; }
            }
            mask |= 1 << bi;
            idx[br * 4 + k] = bi;
        }
    }
}

// ---------------- gathered attention, MFMA version ----------------
__global__ __launch_bounds__(256) void attn_kernel(const float* __restrict__ qkv,
                                                   const int* __restrict__ idx,
                                                   bf16_t* __restrict__ oh,
                                                   bf16_t* __restrict__ ol) {
    __shared__ __align__(16) bf16_t Qh[16 * 72], Ql[16 * 72];
    __shared__ __align__(16) bf16_t Kh[64 * 72], Kl[64 * 72];
    __shared__ __align__(16) bf16_t Vth[64 * 68], Vtl[64 * 68];
    __shared__ __align__(16) float P_s[16 * 68];

    int bid = blockIdx.x;
    int head = bid % 12;
    int r = (bid / 12) % 13;
    int b = bid / (12 * 13);
    int t = threadIdx.x;
    const int lane = t & 63, wave = t >> 6;
    const int quad = lane >> 4, l16 = lane & 15;
    const int co = head * 64;
    const size_t rowb = (size_t)(b * 197);

    int regs[4];
#pragma unroll
    for (int j = 0; j < 4; j++) regs[j] = idx[(b * 13 + r) * 4 + j];

    {
        int rh = t >> 5;          // 0..7
        int c2 = (t & 31) * 2;    // 0..62
#pragma unroll
        for (int it = 0; it < 2; it++) {
            int m = rh + it * 8;
            int tp = r * 16 + m;
            float2 v; v.x = 0.f; v.y = 0.f;
            if (tp < 197) v = *(const float2*)&qkv[(rowb + tp) * 2304 + co + c2];
            bf16_t h0 = f2b(v.x), h1 = f2b(v.y);
            bf16x2v hh = {h0, h1};
            bf16x2v ll = {f2b(v.x - b2f(h0)), f2b(v.y - b2f(h1))};
            *(bf16x2v*)&Qh[m * 72 + c2] = hh;
            *(bf16x2v*)&Ql[m * 72 + c2] = ll;
        }
#pragma unroll
        for (int nb = 0; nb < 4; nb++) {
            int reg = regs[nb];
#pragma unroll
            for (int i2 = 0; i2 < 2; i2++) {
                int nn = rh + i2 * 8;
                int tp = reg * 16 + nn;
                int n = nb * 16 + nn;
                float2 v; v.x = 0.f; v.y = 0.f;
                if (tp < 197) v = *(const float2*)&qkv[(rowb + tp) * 2304 + 768 + co + c2];
                bf16_t h0 = f2b(v.x), h1 = f2b(v.y);
                bf16x2v hh = {h0, h1};
                bf16x2v ll = {f2b(v.x - b2f(h0)), f2b(v.y - b2f(h1))};
                *(bf16x2v*)&Kh[n * 72 + c2] = hh;
                *(bf16x2v*)&Kl[n * 72 + c2] = ll;
            }
        }
    }
    {
        int d = lane;
#pragma unroll
        for (int nb = 0; nb < 4; nb++) {
            int reg = regs[nb];
#pragma unroll
            for (int i2 = 0; i2 < 4; i2++) {
                int nn = wave + i2 * 4;
                int tp = reg * 16 + nn;
                int n = nb * 16 + nn;
                float v = (tp < 197) ? qkv[(rowb + tp) * 2304 + 1536 + co + d] : 0.f;
                bf16_t h = f2b(v);
                Vth[d * 68 + n] = h;
                Vtl[d * 68 + n] = f2b(v - b2f(h));
            }
        }
    }
    __syncthreads();

    {
        const int j = wave;
        bf16x8 qfh[2], qfl[2], kfh[2], kfl[2];
#pragma unroll
        for (int ks = 0; ks < 2; ks++) {
            qfh[ks] = *(const bf16x8*)&Qh[l16 * 72 + ks * 32 + quad * 8];
            qfl[ks] = *(const bf16x8*)&Ql[l16 * 72 + ks * 32 + quad * 8];
            kfh[ks] = *(const bf16x8*)&Kh[(j * 16 + l16) * 72 + ks * 32 + quad * 8];
            kfl[ks] = *(const bf16x8*)&Kl[(j * 16 + l16) * 72 + ks * 32 + quad * 8];
        }
        floatx4 s;
        s[0] = s[1] = s[2] = s[3] = 0.f;
#pragma unroll
        for (int ks = 0; ks < 2; ks++) {
            s = __builtin_amdgcn_mfma_f32_16x16x32_bf16(qfh[ks], kfh[ks], s, 0, 0, 0);
            s = __builtin_amdgcn_mfma_f32_16x16x32_bf16(qfh[ks], kfl[ks], s, 0, 0, 0);
            s = __builtin_amdgcn_mfma_f32_16x16x32_bf16(qfl[ks], kfh[ks], s, 0, 0, 0);
        }
#pragma unroll
        for (int p = 0; p < 4; p++)
            P_s[(quad * 4 + p) * 68 + j * 16 + l16] = s[p] * 0.125f;
    }
    __syncthreads();

    {
        int rw = t >> 4, c = t & 15;
        floatx4 v = *(const floatx4*)&P_s[rw * 68 + c * 4];
        float mx = fmaxf(fmaxf(v[0], v[1]), fmaxf(v[2], v[3]));
#pragma unroll
        for (int msk = 8; msk >= 1; msk >>= 1) mx = fmaxf(mx, __shfl_xor(mx, msk, 64));
        floatx4 e;
        e[0] = expf(v[0] - mx); e[1] = expf(v[1] - mx);
        e[2] = expf(v[2] - mx); e[3] = expf(v[3] - mx);
        float sm = e[0] + e[1] + e[2] + e[3];
#pragma unroll
        for (int msk = 8; msk >= 1; msk >>= 1) sm += __shfl_xor(sm, msk, 64);
        float inv = 1.f / sm;
        e[0] *= inv; e[1] *= inv; e[2] *= inv; e[3] *= inv;
        *(floatx4*)&P_s[rw * 68 + c * 4] = e;
    }
    __syncthreads();

    {
        const int j = wave;
        bf16x8 pfh[2], pfl[2], vfh[2], vfl[2];
#pragma unroll
        for (int ks = 0; ks < 2; ks++) {
            floatx4 p0 = *(const floatx4*)&P_s[l16 * 68 + ks * 32 + quad * 8];
            floatx4 p1 = *(const floatx4*)&P_s[l16 * 68 + ks * 32 + quad * 8 + 4];
#pragma unroll
            for (int i = 0; i < 4; i++) {
                float f0 = p0[i], f1 = p1[i];
                bf16_t h0 = f2b(f0), h1 = f2b(f1);
                pfh[ks][i] = h0;      pfh[ks][4 + i] = h1;
                pfl[ks][i] = f2b(f0 - b2f(h0));
                pfl[ks][4 + i] = f2b(f1 - b2f(h1));
            }
            int vrow = (j * 16 + l16) * 68 + ks * 32 + quad * 8;
            bf16x4 a0 = *(const bf16x4*)&Vth[vrow];
            bf16x4 a1 = *(const bf16x4*)&Vth[vrow + 4];
            bf16x4 c0 = *(const bf16x4*)&Vtl[vrow];
            bf16x4 c1 = *(const bf16x4*)&Vtl[vrow + 4];
#pragma unroll
            for (int i = 0; i < 4; i++) {
                vfh[ks][i] = a0[i]; vfh[ks][4 + i] = a1[i];
                vfl[ks][i] = c0[i]; vfl[ks][4 + i] = c1[i];
            }
        }
        floatx4 o;
        o[0] = o[1] = o[2] = o[3] = 0.f;
#pragma unroll
        for (int ks = 0; ks < 2; ks++) {
            o = __builtin_amdgcn_mfma_f32_16x16x32_bf16(pfh[ks], vfh[ks], o, 0, 0, 0);
            o = __builtin_amdgcn_mfma_f32_16x16x32_bf16(pfh[ks], vfl[ks], o, 0, 0, 0);
            o = __builtin_amdgcn_mfma_f32_16x16x32_bf16(pfl[ks], vfh[ks], o, 0, 0, 0);
        }
#pragma unroll
        for (int p = 0; p < 4; p++) {
            int m = quad * 4 + p;
            int tp = r * 16 + m;
            if (tp < 197) {
                size_t oidx = (rowb + tp) * 768 + co + j * 16 + l16;
                float f = o[p];
                bf16_t h = f2b(f);
                oh[oidx] = h;
                ol[oidx] = f2b(f - b2f(h));
            }
        }
    }
}

// ---------------- extract t[:,0] hi/lo for head GEMM ----------------
__global__ void headx_split(const float* __restrict__ t, bf16_t* __restrict__ oh,
                            bf16_t* __restrict__ ol) {
    int id = blockIdx.x * 256 + threadIdx.x;
    if (id >= 16 * 768) return;
    int b = id / 768, c = id % 768;
    float v = t[((size_t)(b * 197)) * 768 + c];
    bf16_t h = f2b(v);
    oh[id] = h;
    ol[id] = f2b(v - b2f(h));
}

extern "C" void kernel_launch(void* const* d_in, const int* in_sizes, int n_in,
                              void* d_out, int out_size, void* d_ws, size_t ws_size,
                              hipStream_t stream) {
    const float* x      = (const float*)d_in[0];
    const float* conv_w = (const float*)d_in[1];
    const float* conv_b = (const float*)d_in[2];
    const float* cls    = (const float*)d_in[3];
    const float* pos    = (const float*)d_in[4];
    const float* ln1g   = (const float*)d_in[5];
    const float* ln1b   = (const float*)d_in[6];
    const float* qkvw   = (const float*)d_in[7];
    const float* qkvb   = (const float*)d_in[8];
    const float* projw  = (const float*)d_in[9];
    const float* projb  = (const float*)d_in[10];
    const float* ln2g   = (const float*)d_in[11];
    const float* ln2b   = (const float*)d_in[12];
    const float* fc1w   = (const float*)d_in[13];
    const float* fc1b   = (const float*)d_in[14];
    const float* fc2w   = (const float*)d_in[15];
    const float* fc2b   = (const float*)d_in[16];
    const float* headw  = (const float*)d_in[17];
    const float* headb  = (const float*)d_in[18];
    float* out = (float*)d_out;

    char* ws = (char*)d_ws;
    size_t off = 0;
    auto alloc = [&](size_t bytes) -> void* {
        void* p = ws + off;
        off += (bytes + 255) & ~(size_t)255;
        return p;
    };
    // NOTE: allocation ORDER matters — fc2 split-K partials reuse the contiguous
    // dead region [h32, lnHi, lnLo, atHi, atLo] (= exactly 3 x 3152*768 floats).
    float*  tbuf   = (float*)alloc((size_t)3152 * 768 * 4);   // residual stream f32
    float*  h32    = (float*)alloc((size_t)3152 * 768 * 4);   // LN1 f32 out (routing)
    bf16_t* lnHi   = (bf16_t*)alloc((size_t)3152 * 768 * 2);
    bf16_t* lnLo   = (bf16_t*)alloc((size_t)3152 * 768 * 2);
    bf16_t* atHi   = (bf16_t*)alloc((size_t)3152 * 768 * 2);
    bf16_t* atLo   = (bf16_t*)alloc((size_t)3152 * 768 * 2);
    bf16_t* WhiT   = (bf16_t*)alloc((size_t)WTSZ * 2);        // combined layer W^T hi
    bf16_t* WloT   = (bf16_t*)alloc((size_t)WTSZ * 2);        // combined layer W^T lo
    char*   uni    = (char*)alloc((size_t)3152 * 3072 * 2 * 2);
    float*  qkvF   = (float*)uni;
    bf16_t* geHi   = (bf16_t*)uni;
    bf16_t* geLo   = geHi + (size_t)3152 * 3072;
    bf16_t* imHi   = (bf16_t*)uni;
    bf16_t* imLo   = imHi + (size_t)3136 * 768;
    float*  embPar = (float*)(uni + (size_t)3136 * 768 * 2 * 2);
    float*  hsum   = (float*)alloc((size_t)208 * 768 * 4);
    float*  qreg   = (float*)alloc((size_t)208 * 768 * 4);
    float*  kreg   = (float*)alloc((size_t)208 * 768 * 4);
    int*    idx    = (int*)alloc((size_t)832 * 4);
    bf16_t* hdHi   = (bf16_t*)alloc((size_t)16 * 768 * 2);
    bf16_t* hdLo   = (bf16_t*)alloc((size_t)16 * 768 * 2);
    alloc((size_t)1 << 18);  // pad: head GEMM staging reads past hdLo (rows to 127)
    if (off > ws_size) return;  // guard: output stays zero -> clear failure signal

    dim3 blk(256);
    dim3 tblk(32, 8);
    const int RED768 = (3152 * 768 / 4) / 256;   // 2364
    const int REDEMB = (3136 * 768 / 4) / 256;   // 2352
    const size_t PS = (size_t)3152 * 768;

    // ---- patch embed: split-K x3 (Kc=256), partials in uni tail ----
    im2col_split<<<dim3(9408), blk, 0, stream>>>(x, imHi, imLo);
    split_kernel<<<dim3(2304), blk, 0, stream>>>(conv_w, WhiT, WloT, 768 * 768);
    gemm_nts<<<dim3(6, 25, 3), blk, 0, stream>>>(imHi, imLo, WhiT, WloT, nullptr,
                                                 embPar, nullptr, nullptr,
                                                 3136, 768, 768, 256, (size_t)3136 * 768, 0);
    reduce_kernel<<<dim3(REDEMB), blk, 0, stream>>>(embPar, 3, conv_b, tbuf, pos,
                                                    3136, 768, 2);
    clspos_kernel<<<dim3(48), blk, 0, stream>>>(cls, pos, tbuf);

    for (int l = 0; l < 12; l++) {
        ln_kernel<<<dim3(3152), blk, 0, stream>>>(tbuf, ln1g + l * 768, ln1b + l * 768,
                                                  lnHi, lnLo, h32);

        // routing (f32 exact given state)
        regsum_kernel<<<dim3(208), blk, 0, stream>>>(h32, hsum);
        qkreg_gemm<<<dim3(24, 13), blk, 0, stream>>>(hsum, qkvw + (size_t)l * 768 * 2304,
                                                     qkvb + l * 2304, qreg, kreg);
        afftopk_kernel<<<dim3(208), blk, 0, stream>>>(qreg, kreg, idx);

        // qkv W^T immediately before its GEMM (L2 adjacency)
        transpose_all<<<dim3(1728), tblk, 0, stream>>>(qkvw + (size_t)l * 768 * 2304,
                                                       projw + (size_t)l * 768 * 768,
                                                       fc1w + (size_t)l * 768 * 3072,
                                                       fc2w + (size_t)l * 3072 * 768,
                                                       WhiT, WloT, 0);
        // qkv GEMM -> f32 (450 wg, unsplit, mode 1)
        gemm_nts<<<dim3(18, 25, 1), blk, 0, stream>>>(lnHi, lnLo, WhiT, WloT,
                                                      qkvb + l * 2304, qkvF,
                                                      nullptr, nullptr,
                                                      3152, 2304, 768, 768, 0, 1);

        attn_kernel<<<dim3(16 * 13 * 12), blk, 0, stream>>>(qkvF, idx, atHi, atLo);

        // proj W^T immediately before proj GEMM
        transpose_all<<<dim3(576), tblk, 0, stream>>>(qkvw + (size_t)l * 768 * 2304,
                                                      projw + (size_t)l * 768 * 768,
                                                      fc1w + (size_t)l * 768 * 3072,
                                                      fc2w + (size_t)l * 3072 * 768,
                                                      WhiT, WloT, 1728);
        // proj: split-K x4 (Kc=192), partials fill uni exactly (qkvF dead);
        // fused reduce + bias + LN2 -> lnHi/lnLo
        gemm_nts<<<dim3(6, 25, 4), blk, 0, stream>>>(atHi, atLo, WhiT + OPRJ, WloT + OPRJ,
                                                     nullptr, (float*)uni, nullptr, nullptr,
                                                     3152, 768, 768, 192, PS, 0);
        reduce_ln_kernel<<<dim3(3152), blk, 0, stream>>>((float*)uni, 4, PS,
                                                         projb + l * 768,
                                                         ln2g + l * 768, ln2b + l * 768,
                                                         lnHi, lnLo);

        // fc1 W^T immediately before fc1 GEMM
        transpose_all<<<dim3(2304), tblk, 0, stream>>>(qkvw + (size_t)l * 768 * 2304,
                                                       projw + (size_t)l * 768 * 768,
                                                       fc1w + (size_t)l * 768 * 3072,
                                                       fc2w + (size_t)l * 3072 * 768,
                                                       WhiT, WloT, 2304);
        // fc1 (600 wg, unsplit, gelu epilogue)
        gemm_nts<<<dim3(24, 25, 1), blk, 0, stream>>>(lnHi, lnLo, WhiT + OFC1, WloT + OFC1,
                                                      fc1b + l * 3072, nullptr,
                                                      geHi, geLo, 3152, 3072, 768, 768, 0, 2);

        // fc2 W^T immediately before fc2 GEMM
        transpose_all<<<dim3(2304), tblk, 0, stream>>>(qkvw + (size_t)l * 768 * 2304,
                                                       projw + (size_t)l * 768 * 768,
                                                       fc1w + (size_t)l * 768 * 3072,
                                                       fc2w + (size_t)l * 3072 * 768,
                                                       WhiT, WloT, 4608);
        // fc2: split-K x3 (Kc=1024), partials in dead [h32,lnHi,lnLo,atHi,atLo]
        gemm_nts<<<dim3(6, 25, 3), blk, 0, stream>>>(geHi, geLo, WhiT + OFC2, WloT + OFC2,
                                                     nullptr, h32, nullptr, nullptr,
                                                     3152, 768, 3072, 1024, PS, 0);
        reduce_kernel<<<dim3(RED768), blk, 0, stream>>>(h32, 3, fc2b + l * 768,
                                                        tbuf, nullptr, 3152, 768, 1);
    }

    // ---- classification head: split-K x3 (Kc=256), partials in hsum ----
    headx_split<<<dim3(48), blk, 0, stream>>>(tbuf, hdHi, hdLo);
    transpose_split<<<dim3(32, 24), tblk, 0, stream>>>(headw, WhiT, WloT, 768, 1000);
    gemm_nts<<<dim3(8, 1, 3), blk, 0, stream>>>(hdHi, hdLo, WhiT, WloT, nullptr,
                                                hsum, nullptr, nullptr,
                                                16, 1000, 768, 256, (size_t)16 * 1000, 0);
    reduce_kernel<<<dim3(16), blk, 0, stream>>>(hsum, 3, headb, out, nullptr,
                                                16, 1000, 0);
}